// Round 10
// baseline (448.643 us; speedup 1.0000x reference)
//
#include <hip/hip_runtime.h>
#include <hip/hip_bf16.h>
#include <cstdint>

typedef __hip_bfloat16 bf16;
typedef __attribute__((ext_vector_type(8))) __bf16 bfrag;   // MFMA A/B operand (4 VGPRs)
typedef __attribute__((ext_vector_type(4))) float f32x4;    // MFMA C/D operand

#define B_    2
#define S_    1024
#define D_    768
#define H_    12
#define E_    8
#define DH_   64
#define DFF_  2048
#define CAP_  320            // ceil(1.25 * 2048 / 8)
#define CAPP_ 384            // CAP padded to 128-multiple for MFMA tiles
#define NTOK  (B_*S_)        // 2048
#define NTH   (NTOK*H_)      // 24576
#define QKLD  1536           // fused q|k row stride

// ---------------- async global->LDS 16B stage (per-lane global addr, lane-linear LDS) ----------------
__device__ __forceinline__ void stage16(const bf16* g, bf16* ldsLane){
#if __has_builtin(__builtin_amdgcn_global_load_lds)
  __builtin_amdgcn_global_load_lds((const __attribute__((address_space(1))) unsigned int*)g,
                                   (__attribute__((address_space(3))) unsigned int*)ldsLane, 16, 0, 0);
#else
  *(bfrag*)ldsLane = *(const bfrag*)g;
#endif
}

// ---------------- tiled transpose + fp32->bf16 convert: src[K][N] -> dst[N][K] ----------------
__global__ __launch_bounds__(256)
void transp_cvt(const float* __restrict__ src, bf16* __restrict__ dst,
                int K, int N, long sSrc, long sDst, int dstRowOff)
{
  src += (long)blockIdx.z*sSrc;
  dst += (long)blockIdx.z*sDst;
  __shared__ float t[32][33];
  int n0 = blockIdx.x*32, k0 = blockIdx.y*32;
  int tx = threadIdx.x & 31, ty = threadIdx.x >> 5;  // 32 x 8
#pragma unroll
  for (int r=0;r<4;r++){
    int kk = k0 + ty + r*8, nn = n0 + tx;
    t[ty+r*8][tx] = (nn < N) ? src[(long)kk*N + nn] : 0.f;
  }
  __syncthreads();
#pragma unroll
  for (int r=0;r<4;r++){
    int nn = n0 + ty + r*8;
    if (nn < N) dst[(long)(dstRowOff + nn)*K + k0 + tx] = __float2bfloat16(t[tx][ty+r*8]);
  }
}

// ---------------- tiled transpose fp32->fp32: src[K][N] -> dst[N][K] ----------------
__global__ __launch_bounds__(256)
void transp_f32(const float* __restrict__ src, float* __restrict__ dst, int K, int N)
{
  __shared__ float t[32][33];
  int n0 = blockIdx.x*32, k0 = blockIdx.y*32;
  int tx = threadIdx.x & 31, ty = threadIdx.x >> 5;  // 32 x 8
#pragma unroll
  for (int r=0;r<4;r++){
    int kk = k0 + ty + r*8, nn = n0 + tx;
    t[ty+r*8][tx] = (nn < N) ? src[(long)kk*N + nn] : 0.f;
  }
  __syncthreads();
#pragma unroll
  for (int r=0;r<4;r++){
    int nn = n0 + ty + r*8;
    if (nn < N) dst[(long)nn*K + k0 + tx] = t[tx][ty+r*8];
  }
}

// ---------------- MFMA GEMM, 128x64 tile, xor-swizzled LDS (rows 32 bf16, g ^= row&3) ----------------
__global__ __launch_bounds__(256)
void gemm_bn64(const bf16* __restrict__ A, const bf16* __restrict__ Bt, void* __restrict__ C,
               int M, int N, int K, long sA, long sB, long sC, int relu, int outBf)
{
  A  += (long)blockIdx.z*sA;
  Bt += (long)blockIdx.z*sB;
  int m0 = blockIdx.y*128, n0 = blockIdx.x*64;
  __shared__ bf16 As[128*32];   // 8 KB
  __shared__ bf16 Bs[64*32];    // 4 KB
  int tid = threadIdx.x;
  int w = tid >> 6, lane = tid & 63;
  int quad = lane >> 4, l16 = lane & 15;
  int wm = w*32;
  f32x4 acc[2][4] = {};
  int srow = (lane >> 2);          // row within 16-row chunk
  int gsw  = ((lane & 3) ^ (srow & 3))*8;   // swizzled col group (8 bf16)
  const bf16* aBase = A + (long)m0*K;
  const bf16* bBase = Bt + (long)n0*K;
  int xr = (l16 & 3);              // read-side swizzle key (row&3 == l16&3)
  for (int k0=0; k0<K; k0+=32){
#pragma unroll
    for (int j=0;j<2;j++){
      int c = w*2 + j;
      int row = c*16 + srow;
      stage16(aBase + (long)row*K + k0 + gsw, As + c*512 + lane*8);
    }
    {
      int row = w*16 + srow;
      stage16(bBase + (long)row*K + k0 + gsw, Bs + w*512 + lane*8);
    }
    __syncthreads();
    bfrag af[2], bfv[4];
#pragma unroll
    for (int t=0;t<2;t++) af[t]  = *(const bfrag*)(As + (wm + t*16 + l16)*32 + ((quad ^ xr)*8));
#pragma unroll
    for (int t=0;t<4;t++) bfv[t] = *(const bfrag*)(Bs + (t*16 + l16)*32 + ((quad ^ xr)*8));
#pragma unroll
    for (int ti=0;ti<2;ti++)
#pragma unroll
      for (int tj=0;tj<4;tj++)
        acc[ti][tj] = __builtin_amdgcn_mfma_f32_16x16x32_bf16(af[ti], bfv[tj], acc[ti][tj], 0, 0, 0);
    __syncthreads();
  }
  long zoff = (long)blockIdx.z*sC;
  if (outBf){
    bf16* Cb = (bf16*)C + zoff;
#pragma unroll
    for (int ti=0;ti<2;ti++)
#pragma unroll
      for (int tj=0;tj<4;tj++)
#pragma unroll
        for (int r=0;r<4;r++){
          int row = m0 + wm + ti*16 + quad*4 + r;
          int col = n0 + tj*16 + l16;
          float v = acc[ti][tj][r];
          if (relu) v = fmaxf(v, 0.f);
          Cb[(long)row*N + col] = __float2bfloat16(v);
        }
  } else {
    float* Cf = (float*)C + zoff;
#pragma unroll
    for (int ti=0;ti<2;ti++)
#pragma unroll
      for (int tj=0;tj<4;tj++)
#pragma unroll
        for (int r=0;r<4;r++){
          int row = m0 + wm + ti*16 + quad*4 + r;
          int col = n0 + tj*16 + l16;
          float v = acc[ti][tj][r];
          if (relu) v = fmaxf(v, 0.f);
          Cf[(long)row*N + col] = v;
        }
  }
}

// ---------------- LayerNorm: fp32 in -> fp32 out (+ optional bf16 copy, + optional fused gate logits) ----------------
__global__ __launch_bounds__(256)
void ln_kernel(const float* __restrict__ src, const float* __restrict__ g, const float* __restrict__ bb,
               float* __restrict__ dstF, bf16* __restrict__ dstB,
               const float* __restrict__ gateW, float* __restrict__ glog2)
{
  int row = blockIdx.x, tid = threadIdx.x;
  __shared__ float red[256];
  __shared__ float gsum[4][E_];
  float v[3];
#pragma unroll
  for (int j=0;j<3;j++) v[j] = src[(long)row*D_ + tid + j*256];
  float s = v[0]+v[1]+v[2];
  red[tid]=s; __syncthreads();
  for (int o=128;o>0;o>>=1){ if(tid<o) red[tid]+=red[tid+o]; __syncthreads(); }
  float mean = red[0]*(1.0f/D_);
  __syncthreads();
  float sq = 0.f;
#pragma unroll
  for (int j=0;j<3;j++){ float d=v[j]-mean; sq += d*d; }
  red[tid]=sq; __syncthreads();
  for (int o=128;o>0;o>>=1){ if(tid<o) red[tid]+=red[tid+o]; __syncthreads(); }
  float rstd = rsqrtf(red[0]*(1.0f/D_) + 1e-5f);
  float ov[3];
#pragma unroll
  for (int j=0;j<3;j++){
    int d = tid + j*256;
    float o = (v[j]-mean)*rstd*g[d] + bb[d];
    ov[j] = o;
    dstF[(long)row*D_+d] = o;
    if (dstB) dstB[(long)row*D_+d] = __float2bfloat16(o);
  }
  if (gateW){
    float gp[E_] = {};
#pragma unroll
    for (int j=0;j<3;j++){
      int d = tid + j*256;
      const float* gw = gateW + (long)d*E_;
#pragma unroll
      for (int e=0;e<E_;e++) gp[e] += ov[j]*gw[e];
    }
#pragma unroll
    for (int off=1; off<64; off<<=1)
#pragma unroll
      for (int e=0;e<E_;e++) gp[e] += __shfl_xor(gp[e], off);
    if ((tid & 63) == 0)
#pragma unroll
      for (int e=0;e<E_;e++) gsum[tid>>6][e] = gp[e];
    __syncthreads();
    if (tid < E_)
      glog2[(long)row*E_ + tid] = gsum[0][tid]+gsum[1][tid]+gsum[2][tid]+gsum[3][tid];
  }
}

// ---------------- router logits + argmax: fp32, 8-way K-parallel; also builds (h,e) histogram ----------------
#define RTOK 4
__global__ __launch_bounds__(768)
void router_argmax(const float* __restrict__ ln1, const float* __restrict__ WrT,
                   int* __restrict__ eidx, int* __restrict__ gHist)
{
  int tok0 = blockIdx.x*RTOK;
  int tid = threadIdx.x;
  int col = tid >> 3, seg = tid & 7;     // col 0..95 (= h*8+e), seg 0..7
  __shared__ float xrow[RTOK][D_];
  __shared__ float logits[RTOK][96];
  for (int i=tid; i<RTOK*D_; i+=768){
    int t = i / D_, dpos = i - t*D_;
    xrow[t][dpos] = ln1[(long)(tok0+t)*D_ + dpos];
  }
  __syncthreads();
  const float4* wp = (const float4*)(WrT + (long)col*D_ + seg*96);
  float acc[RTOK] = {};
#pragma unroll
  for (int j=0;j<24;j++){
    float4 w = wp[j];
    int dbase = seg*96 + j*4;
#pragma unroll
    for (int t=0;t<RTOK;t++){
      const float* xr = &xrow[t][dbase];
      acc[t] += xr[0]*w.x + xr[1]*w.y + xr[2]*w.z + xr[3]*w.w;
    }
  }
#pragma unroll
  for (int off=1; off<8; off<<=1)
#pragma unroll
    for (int t=0;t<RTOK;t++) acc[t] += __shfl_xor(acc[t], off);
  if (seg == 0)
#pragma unroll
    for (int t=0;t<RTOK;t++) logits[t][col] = acc[t];
  __syncthreads();
  if (tid < RTOK*H_){
    int t = tid / H_, h = tid % H_;
    const float* p = &logits[t][h*8];
    float best = p[0]; int bi = 0;
#pragma unroll
    for (int e=1;e<8;e++){ float v=p[e]; if (v > best){ best=v; bi=e; } }
    eidx[(tok0+t)*H_ + h] = bi;
    atomicAdd(&gHist[h*E_ + bi], 1);
  }
}

// ---------------- selected V projection -> transposed bf16 vT[bh][f][s] ----------------
__global__ __launch_bounds__(64)
void vsel_kernel(const float* __restrict__ ln1, const float* __restrict__ Wv,
                 const int* __restrict__ eidx, bf16* __restrict__ vT)
{
  int blk = blockIdx.x;          // tok*H + h
  int h = blk % H_, tok = blk / H_;
  int b = tok >> 10, s = tok & 1023;
  int f = threadIdx.x;
  __shared__ float xs[DH_];
  xs[f] = ln1[(long)tok*D_ + h*DH_ + f];
  __syncthreads();
  int e = eidx[blk];
  const float* W = Wv + (long)(h*E_+e)*DH_*DH_;
  float acc = 0.f;
#pragma unroll 8
  for (int d=0; d<DH_; d++) acc += xs[d]*W[d*DH_ + f];
  vT[((long)(b*H_+h)*DH_ + f)*S_ + s] = __float2bfloat16(acc);
}

// ---------------- attention pass 1 (MFMA flash stats), xor-swizzled 64x64 LDS tiles ----------------
__global__ __launch_bounds__(256)
void attn_stats_mfma(const bf16* __restrict__ qkB, float* __restrict__ gM, float* __restrict__ gL)
{
  int s0 = blockIdx.x*64;
  int h = blockIdx.y, b = blockIdx.z;
  int tid = threadIdx.x;
  int w = tid >> 6, lane = tid & 63;
  int quad = lane >> 4, l16 = lane & 15;
  int x7 = l16 & 7;                    // read-side swizzle key (row&7 == l16&7)
  __shared__ bf16 ldsQ[64*64];
  __shared__ bf16 ldsK[64*64];
  const bf16* qbase = qkB + ((long)(b*S_ + s0))*QKLD + h*DH_;
#pragma unroll
  for (int j=0;j<2;j++){
    int c = j*256 + tid;
    int row = c >> 3;
    int gs = ((c & 7) ^ (row & 7))*8;
    stage16(qbase + (long)row*QKLD + gs, ldsQ + c*8);
  }
  float m_run[4] = {-1e30f,-1e30f,-1e30f,-1e30f};
  float l_run[4] = {0.f,0.f,0.f,0.f};
  const bf16* kbase = qkB + ((long)(b*S_))*QKLD + 768 + h*DH_;
  int ttEnd = s0 >> 6;
  for (int tt=0; tt<=ttEnd; tt++){
    __syncthreads();
#pragma unroll
    for (int j=0;j<2;j++){
      int c = j*256 + tid;
      int row = c >> 3;
      int gs = ((c & 7) ^ (row & 7))*8;
      stage16(kbase + (long)(tt*64 + row)*QKLD + gs, ldsK + c*8);
    }
    __syncthreads();
    bfrag af0 = *(const bfrag*)(ldsQ + (w*16 + l16)*64 + ((quad     ^ x7)*8));
    bfrag af1 = *(const bfrag*)(ldsQ + (w*16 + l16)*64 + (((quad+4) ^ x7)*8));
    f32x4 cfr[4];
#pragma unroll
    for (int j=0;j<4;j++){
      bfrag b0 = *(const bfrag*)(ldsK + (j*16 + l16)*64 + ((quad     ^ x7)*8));
      bfrag b1 = *(const bfrag*)(ldsK + (j*16 + l16)*64 + (((quad+4) ^ x7)*8));
      f32x4 z = {};
      z = __builtin_amdgcn_mfma_f32_16x16x32_bf16(af0, b0, z, 0,0,0);
      z = __builtin_amdgcn_mfma_f32_16x16x32_bf16(af1, b1, z, 0,0,0);
      cfr[j] = z;
    }
#pragma unroll
    for (int r=0;r<4;r++){
      int s_g = s0 + w*16 + quad*4 + r;
      float v[4];
#pragma unroll
      for (int j=0;j<4;j++){
        int t_g = tt*64 + j*16 + l16;
        v[j] = (t_g <= s_g) ? cfr[j][r]*0.125f : -1e30f;
      }
      float mt = fmaxf(fmaxf(v[0],v[1]), fmaxf(v[2],v[3]));
#pragma unroll
      for (int mm=1; mm<16; mm<<=1) mt = fmaxf(mt, __shfl_xor(mt, mm));
      float mn = fmaxf(m_run[r], mt);
      float sum = __expf(v[0]-mn)+__expf(v[1]-mn)+__expf(v[2]-mn)+__expf(v[3]-mn);
#pragma unroll
      for (int mm=1; mm<16; mm<<=1) sum += __shfl_xor(sum, mm);
      l_run[r] = l_run[r]*__expf(m_run[r]-mn) + sum;
      m_run[r] = mn;
    }
  }
  if (l16 == 0){
    long base = ((long)(b*H_ + h))*S_ + s0 + w*16 + quad*4;
#pragma unroll
    for (int r=0;r<4;r++){ gM[base+r] = m_run[r]; gL[base+r] = l_run[r]; }
  }
}

// ---------------- attention pass 2 (fused MFMA, transposed einsum), swizzled LDS + padded ldsS ----------------
__global__ __launch_bounds__(256)
void attn_pv(const bf16* __restrict__ qkB, const bf16* __restrict__ vT,
             const float* __restrict__ gM, const float* __restrict__ gL, float* __restrict__ aoH)
{
  int t0 = blockIdx.x*64;
  int h = blockIdx.y, b = blockIdx.z;
  int bh = b*H_ + h;
  int tid = threadIdx.x;
  int w = tid >> 6, lane = tid & 63;
  int quad = lane >> 4, l16 = lane & 15;
  int x7 = l16 & 7;
  __shared__ bf16 ldsK[64*64];
  __shared__ bf16 ldsQ[64*64];
  __shared__ bf16 ldsV[64*64];
  __shared__ bf16 ldsS[64*72];        // +8 pad breaks write-side bank conflicts
  __shared__ float smx[64], sli[64];
  const bf16* kbase = qkB + ((long)(b*S_ + t0))*QKLD + 768 + h*DH_;
#pragma unroll
  for (int j=0;j<2;j++){
    int c = j*256 + tid;
    int row = c >> 3;
    int gs = ((c & 7) ^ (row & 7))*8;
    stage16(kbase + (long)row*QKLD + gs, ldsK + c*8);
  }
  f32x4 accO[4] = {};
  const bf16* qbase = qkB + ((long)(b*S_))*QKLD + h*DH_;
  const bf16* vbase = vT + ((long)bh*DH_)*S_;
  for (int sb = t0>>6; sb < S_/64; sb++){
    __syncthreads();
#pragma unroll
    for (int j=0;j<2;j++){
      int c = j*256 + tid;
      int row = c >> 3;
      int gs = ((c & 7) ^ (row & 7))*8;
      stage16(qbase + (long)(sb*64 + row)*QKLD + gs, ldsQ + c*8);
      stage16(vbase + (long)row*S_ + sb*64 + gs, ldsV + c*8);
    }
    if (tid < 64){
      smx[tid] = gM[(long)bh*S_ + sb*64 + tid];
      sli[tid] = 1.0f / gL[(long)bh*S_ + sb*64 + tid];
    }
    __syncthreads();
    bfrag af0 = *(const bfrag*)(ldsK + (w*16 + l16)*64 + ((quad     ^ x7)*8));
    bfrag af1 = *(const bfrag*)(ldsK + (w*16 + l16)*64 + (((quad+4) ^ x7)*8));
    f32x4 cs[4];
#pragma unroll
    for (int j=0;j<4;j++){
      bfrag b0 = *(const bfrag*)(ldsQ + (j*16 + l16)*64 + ((quad     ^ x7)*8));
      bfrag b1 = *(const bfrag*)(ldsQ + (j*16 + l16)*64 + (((quad+4) ^ x7)*8));
      f32x4 z = {};
      z = __builtin_amdgcn_mfma_f32_16x16x32_bf16(af0, b0, z, 0,0,0);
      z = __builtin_amdgcn_mfma_f32_16x16x32_bf16(af1, b1, z, 0,0,0);
      cs[j] = z;
    }
#pragma unroll
    for (int j=0;j<4;j++)
#pragma unroll
      for (int r=0;r<4;r++){
        int t_loc = w*16 + quad*4 + r;
        int s_loc = j*16 + l16;
        float wgt = ((t0 + t_loc) <= (sb*64 + s_loc))
                  ? __expf(cs[j][r]*0.125f - smx[s_loc])*sli[s_loc] : 0.f;
        ldsS[t_loc*72 + s_loc] = __float2bfloat16(wgt);
      }
    bfrag pa0 = *(const bfrag*)(ldsS + (w*16 + l16)*72 + quad*8);
    bfrag pa1 = *(const bfrag*)(ldsS + (w*16 + l16)*72 + 32 + quad*8);
#pragma unroll
    for (int j=0;j<4;j++){
      bfrag b0 = *(const bfrag*)(ldsV + (j*16 + l16)*64 + ((quad     ^ x7)*8));
      bfrag b1 = *(const bfrag*)(ldsV + (j*16 + l16)*64 + (((quad+4) ^ x7)*8));
      accO[j] = __builtin_amdgcn_mfma_f32_16x16x32_bf16(pa0, b0, accO[j], 0,0,0);
      accO[j] = __builtin_amdgcn_mfma_f32_16x16x32_bf16(pa1, b1, accO[j], 0,0,0);
    }
  }
#pragma unroll
  for (int j=0;j<4;j++)
#pragma unroll
    for (int r=0;r<4;r++){
      int t_loc = w*16 + quad*4 + r;
      int f = j*16 + l16;
      aoH[((long)bh*S_ + t0 + t_loc)*DH_ + f] = accO[j][r];
    }
}

// ---------------- O projection + residual -> x1 ----------------
__global__ __launch_bounds__(64)
void oproj_kernel(const float* __restrict__ aoH, const float* __restrict__ Wo,
                  const int* __restrict__ eidx, const float* __restrict__ x,
                  float* __restrict__ x1)
{
  int blk = blockIdx.x;          // tok*H + h
  int h = blk % H_, tok = blk / H_;
  int b = tok >> 10, s = tok & 1023;
  int g = threadIdx.x;
  __shared__ float xs[DH_];
  xs[g] = aoH[((long)(b*H_+h)*S_ + s)*DH_ + g];
  __syncthreads();
  int e = eidx[blk];
  const float* W = Wo + (long)(h*E_+e)*DH_*DH_;
  float acc = 0.f;
#pragma unroll 8
  for (int f=0; f<DH_; f++) acc += xs[f]*W[f*DH_ + g];
  long idx = (long)tok*D_ + h*DH_ + g;
  x1[idx] = x[idx] + acc;
}

// ---------------- MoE routing: top-2, PARALLEL capacity prefix-scan, lists, aux losses ----------------
__global__ __launch_bounds__(256)
void route_kernel(const float* __restrict__ glog2, const int* __restrict__ gHist,
                  int* __restrict__ gI0, int* __restrict__ gI1,
                  int* __restrict__ gPos0, int* __restrict__ gPos1,
                  int* __restrict__ listTok, float* __restrict__ listW,
                  int* __restrict__ gCnt, float* __restrict__ auxOut)
{
  __shared__ unsigned char sI0[NTOK], sI1[NTOK];
  __shared__ float sP0[NTOK], sP1[NTOK];
  __shared__ short sPos0[NTOK], sPos1[NTOK];
  __shared__ int   sScan[256*E_];
  __shared__ int   sHist[H_*E_];
  __shared__ float sImp[E_];
  __shared__ int   sCnt[E_];
  int tid = threadIdx.x;
  if (tid < E_) sImp[tid] = 0.f;
  if (tid < H_*E_) sHist[tid] = gHist[tid];   // histogram precomputed by router_argmax
  for (int i=tid; i<NTOK; i+=256){
    const float* p = glog2 + (long)i*E_;
    float b0 = p[0]; int e0 = 0;
#pragma unroll
    for (int e=1;e<E_;e++){ float vv=p[e]; if (vv > b0){ b0=vv; e0=e; } }
    float b1v = -1e30f; int e1 = 0;
#pragma unroll
    for (int e=0;e<E_;e++){ if (e==e0) continue; float vv=p[e]; if (vv > b1v){ b1v=vv; e1=e; } }
    float ex = __expf(b1v - b0);
    float inv = 1.f/(1.f + ex);
    sI0[i] = (unsigned char)e0; sI1[i] = (unsigned char)e1;
    sP0[i] = inv; sP1[i] = ex*inv;
    gI0[i] = e0; gI1[i] = e1;
  }
  __syncthreads();
  {
    int myCnt[E_] = {};
#pragma unroll
    for (int j=0;j<16;j++){
      int i = tid*16 + j;
      int tok = i >> 1;
      int e = (i & 1) ? (int)sI1[tok] : (int)sI0[tok];
      myCnt[e]++;
    }
#pragma unroll
    for (int e=0;e<E_;e++) sScan[tid*E_+e] = myCnt[e];
    __syncthreads();
    for (int off=1; off<256; off<<=1){
      int v[E_];
      if (tid >= off){
#pragma unroll
        for (int e=0;e<E_;e++) v[e] = sScan[(tid-off)*E_+e];
      }
      __syncthreads();
      if (tid >= off){
#pragma unroll
        for (int e=0;e<E_;e++) sScan[tid*E_+e] += v[e];
      }
      __syncthreads();
    }
    int pref[E_];
#pragma unroll
    for (int e=0;e<E_;e++) pref[e] = tid ? sScan[(tid-1)*E_+e] : 0;
#pragma unroll
    for (int j=0;j<16;j++){
      int i = tid*16 + j;
      int tok = i >> 1;
      int e = (i & 1) ? (int)sI1[tok] : (int)sI0[tok];
      int pos = pref[e]++;
      short p = (pos < CAP_) ? (short)pos : (short)-1;
      if (i & 1) sPos1[tok] = p; else sPos0[tok] = p;
    }
    if (tid < E_){
      int cnt = sScan[255*E_ + tid];
      sCnt[tid] = cnt < CAP_ ? cnt : CAP_;
      gCnt[tid] = sCnt[tid];
    }
  }
  __syncthreads();
  for (int i=tid; i<NTOK; i+=256){
    int e0 = sI0[i], e1 = sI1[i];
    int p0i = sPos0[i], p1i = sPos1[i];
    float k0 = p0i >= 0 ? 1.f : 0.f, k1 = p1i >= 0 ? 1.f : 0.f;
    float p0 = sP0[i], p1 = sP1[i];
    float denom = p0*k0 + p1*k1 + 1e-9f;
    float w0 = p0*k0/denom, w1 = p1*k1/denom;
    if (p0i >= 0){ listTok[e0*CAP_+p0i] = i; listW[e0*CAP_+p0i] = w0; atomicAdd(&sImp[e0], w0); }
    if (p1i >= 0){ listTok[e1*CAP_+p1i] = i; listW[e1*CAP_+p1i] = w1; atomicAdd(&sImp[e1], w1); }
    gPos0[i] = p0i; gPos1[i] = p1i;
  }
  __syncthreads();
  if (tid == 0){
    float tot = 0.f;
    for (int i=0;i<H_*E_;i++) tot += (float)sHist[i]*(1.0f/NTOK)*0.01f;
    float a1 = 0.f;
    for (int i=0;i<H_*E_;i++){
      float p = ((float)sHist[i]*(1.0f/NTOK)*0.01f)/(tot + 1e-9f);
      a1 += p*p;
    }
    a1 *= (float)(H_*E_);
    float tcs = 0.f, ims = 0.f;
    for (int e=0;e<E_;e++){ tcs += (float)sCnt[e]; ims += sImp[e]; }
    float a2 = 0.f;
    for (int e=0;e<E_;e++) a2 += ((float)sCnt[e]/tcs)*(sImp[e]/ims);
    a2 *= (float)E_;
    auxOut[0] = a1 + a2;
  }
}

// ---------------- gather scaled tokens per expert -> bf16 Xg (CAPP rows/expert, zero-padded) ----------------
__global__ __launch_bounds__(256)
void gather_kernel(const float* __restrict__ ln2, const int* __restrict__ listTok,
                   const float* __restrict__ listW, const int* __restrict__ gCnt,
                   bf16* __restrict__ Xg)
{
  int blk = blockIdx.x;          // e*CAPP_ + r
  int e = blk / CAPP_, r = blk % CAPP_;
  int tid = threadIdx.x;
  bool live = r < gCnt[e];
  int tok = 0; float w = 0.f;
  if (live){ tok = listTok[e*CAP_+r]; w = listW[e*CAP_+r]; }
  for (int d=tid; d<D_; d+=256)
    Xg[(long)blk*D_ + d] = __float2bfloat16(live ? ln2[(long)tok*D_+d]*w : 0.f);
}

// ---------------- final combine: out = x1 + expert contributions (fp32 output) ----------------
__global__ __launch_bounds__(256)
void combine_kernel(const float* __restrict__ x1, const float* __restrict__ Yexp,
                    const int* __restrict__ gI0, const int* __restrict__ gI1,
                    const int* __restrict__ gPos0, const int* __restrict__ gPos1,
                    float* __restrict__ out)
{
  int i = blockIdx.x;
  int tid = threadIdx.x;
  int p0 = gPos0[i], p1 = gPos1[i];
  int e0 = gI0[i],  e1 = gI1[i];
  const float* y0 = Yexp + (long)(e0*CAPP_ + (p0 >= 0 ? p0 : 0))*D_;
  const float* y1 = Yexp + (long)(e1*CAPP_ + (p1 >= 0 ? p1 : 0))*D_;
  for (int d=tid; d<D_; d+=256){
    float v = x1[(long)i*D_+d];
    if (p0 >= 0) v += y0[d];
    if (p1 >= 0) v += y1[d];
    out[(long)i*D_+d] = v;
  }
}

extern "C" void kernel_launch(void* const* d_in, const int* in_sizes, int n_in,
                              void* d_out, int out_size, void* d_ws, size_t ws_size,
                              hipStream_t stream)
{
  const float* x    = (const float*)d_in[0];
  const float* W_q  = (const float*)d_in[2];
  const float* W_k  = (const float*)d_in[3];
  const float* W_v  = (const float*)d_in[4];
  const float* W_o  = (const float*)d_in[5];
  const float* W_r  = (const float*)d_in[6];
  const float* g1   = (const float*)d_in[7];
  const float* b1   = (const float*)d_in[8];
  const float* g2   = (const float*)d_in[9];
  const float* b2   = (const float*)d_in[10];
  const float* gate = (const float*)d_in[11];
  const float* W1   = (const float*)d_in[12];
  const float* W2   = (const float*)d_in[13];
  float* out = (float*)d_out;

  float* wsf = (float*)d_ws;
  // ---- workspace layout (float slots) ----
  const long oX1   = 0;          // 1,572,864
  const long oLnF  = 1572864;
  const long oLnB  = 3145728;    // bf16 2048x768
  const long oWcat = 3932160;    // bf16 1536x768 (ends 4521984)
  const long oWrT  = 4521984;    // fp32 96x768 = 73,728 (ends 4595712)
  const long oHist = 4595712;    // int 96 (attention (h,e) histogram)
  const long oGM   = 4718592;    // 24,576
  const long oGL   = 4743168;    // 24,576
  const long oEidx = 4767744;    // int 24,576
  const long oGlg2 = 4792320;    // 16,384
  const long oI0   = 4808704;
  const long oI1   = 4810752;
  const long oP0   = 4812800;
  const long oP1   = 4814848;
  const long oLT   = 4816896;
  const long oLW   = 4819456;
  const long oCnt  = 4822016;
  const long SB    = 4822528;    // shared overlay region
  // attention view: qkB bf16 @SB (1.57M) | vT bf16 @+1,572,864 (0.79M) | aoH fp32 @+2,359,296 (1.57M)
  // FFN view:       WT bf16 @SB (6.29M) | Xg @+6,291,456 | Hid @+7,471,104 | Yexp fp32 @+10,616,832
  const long TOTAL = SB + 12976128;   // 17,798,656 floats = 71,194,624 B
  if (ws_size < (size_t)TOTAL*4) return;

  float* x1    = wsf + oX1;
  float* lnbF  = wsf + oLnF;
  bf16*  lnbB  = (bf16*)(wsf + oLnB);
  bf16*  WcatB = (bf16*)(wsf + oWcat);
  float* WrT   = wsf + oWrT;
  int*   gHist = (int*)(wsf + oHist);
  float* gM    = wsf + oGM;
  float* gL    = wsf + oGL;
  int*   eidx  = (int*)(wsf + oEidx);
  float* glog2 = wsf + oGlg2;
  int*   gI0   = (int*)(wsf + oI0);
  int*   gI1   = (int*)(wsf + oI1);
  int*   gPos0 = (int*)(wsf + oP0);
  int*   gPos1 = (int*)(wsf + oP1);
  int*   lTok  = (int*)(wsf + oLT);
  float* lW    = wsf + oLW;
  int*   gCnt  = (int*)(wsf + oCnt);
  bf16*  qkB   = (bf16*)(wsf + SB);
  bf16*  vT    = (bf16*)(wsf + SB + 1572864);
  float* aoH   = wsf + SB + 2359296;
  bf16*  WT    = (bf16*)(wsf + SB);
  bf16*  Xg    = (bf16*)(wsf + SB + 6291456);
  bf16*  Hid   = (bf16*)(wsf + SB + 7471104);
  float* Yexp  = wsf + SB + 10616832;

  // ---- weight prep + hist zero ----
  hipMemsetAsync(gHist, 0, H_*E_*sizeof(int), stream);
  transp_cvt<<<dim3(24,24,1),256,0,stream>>>(W_q, WcatB, 768, 768, 0, 0, 0);
  transp_cvt<<<dim3(24,24,1),256,0,stream>>>(W_k, WcatB, 768, 768, 0, 0, 768);
  transp_f32<<<dim3(3,24,1),256,0,stream>>>(W_r, WrT, 768, 96);

  // ---- attention phase ----
  ln_kernel<<<NTOK,256,0,stream>>>(x, g1, b1, lnbF, lnbB, nullptr, nullptr);
  gemm_bn64<<<dim3(24,16,1),256,0,stream>>>(lnbB, WcatB, qkB, 2048, QKLD, 768, 0,0,0, 0, 1);
  router_argmax<<<NTOK/RTOK,768,0,stream>>>(lnbF, WrT, eidx, gHist);
  vsel_kernel<<<NTH,64,0,stream>>>(lnbF, W_v, eidx, vT);
  attn_stats_mfma<<<dim3(S_/64,H_,B_),256,0,stream>>>(qkB, gM, gL);
  attn_pv<<<dim3(S_/64,H_,B_),256,0,stream>>>(qkB, vT, gM, gL, aoH);
  oproj_kernel<<<NTH,64,0,stream>>>(aoH, W_o, eidx, x, x1);

  // ---- FFN phase ----
  ln_kernel<<<NTOK,256,0,stream>>>(x1, g2, b2, lnbF, nullptr, gate, glog2);  // fused gate logits
  route_kernel<<<1,256,0,stream>>>(glog2, gHist, gI0,gI1,gPos0,gPos1, lTok,lW,gCnt, out + (size_t)NTOK*D_);
  gather_kernel<<<E_*CAPP_,256,0,stream>>>(lnbF, lTok, lW, gCnt, Xg);
  transp_cvt<<<dim3(64,24,8),256,0,stream>>>(W1, WT, 768, 2048, (long)768*2048, (long)2048*768, 0);
  gemm_bn64<<<dim3(32,3,8),256,0,stream>>>(Xg, WT, Hid, CAPP_, DFF_, 768,
                                           (long)CAPP_*768, (long)2048*768, (long)CAPP_*2048, 1, 1);
  transp_cvt<<<dim3(24,64,8),256,0,stream>>>(W2, WT, 2048, 768, (long)2048*768, (long)768*2048, 0);
  gemm_bn64<<<dim3(12,3,8),256,0,stream>>>(Hid, WT, Yexp, CAPP_, 768, 2048,
                                           (long)CAPP_*2048, (long)768*2048, (long)CAPP_*768, 0, 0);
  combine_kernel<<<NTOK,256,0,stream>>>(x1, Yexp, gI0,gI1,gPos0,gPos1, out);
}

// Round 11
// 438.918 us; speedup vs baseline: 1.0222x; 1.0222x over previous
//
#include <hip/hip_runtime.h>
#include <hip/hip_bf16.h>
#include <cstdint>

typedef __hip_bfloat16 bf16;
typedef __attribute__((ext_vector_type(8))) __bf16 bfrag;   // MFMA A/B operand (4 VGPRs)
typedef __attribute__((ext_vector_type(4))) float f32x4;    // MFMA C/D operand

#define B_    2
#define S_    1024
#define D_    768
#define H_    12
#define E_    8
#define DH_   64
#define DFF_  2048
#define CAP_  320            // ceil(1.25 * 2048 / 8)
#define CAPP_ 384            // CAP padded to 128-multiple for MFMA tiles
#define NTOK  (B_*S_)        // 2048
#define NTH   (NTOK*H_)      // 24576
#define QKLD  1536           // fused q|k row stride

// ---------------- async global->LDS 16B stage (per-lane global addr, lane-linear LDS) ----------------
__device__ __forceinline__ void stage16(const bf16* g, bf16* ldsLane){
#if __has_builtin(__builtin_amdgcn_global_load_lds)
  __builtin_amdgcn_global_load_lds((const __attribute__((address_space(1))) unsigned int*)g,
                                   (__attribute__((address_space(3))) unsigned int*)ldsLane, 16, 0, 0);
#else
  *(bfrag*)ldsLane = *(const bfrag*)g;
#endif
}

// ---------------- tiled transpose + fp32->bf16 convert: src[K][N] -> dst[N][K] ----------------
__global__ __launch_bounds__(256)
void transp_cvt(const float* __restrict__ src, bf16* __restrict__ dst,
                int K, int N, long sSrc, long sDst, int dstRowOff)
{
  src += (long)blockIdx.z*sSrc;
  dst += (long)blockIdx.z*sDst;
  __shared__ float t[32][33];
  int n0 = blockIdx.x*32, k0 = blockIdx.y*32;
  int tx = threadIdx.x & 31, ty = threadIdx.x >> 5;  // 32 x 8
#pragma unroll
  for (int r=0;r<4;r++){
    int kk = k0 + ty + r*8, nn = n0 + tx;
    t[ty+r*8][tx] = (nn < N) ? src[(long)kk*N + nn] : 0.f;
  }
  __syncthreads();
#pragma unroll
  for (int r=0;r<4;r++){
    int nn = n0 + ty + r*8;
    if (nn < N) dst[(long)(dstRowOff + nn)*K + k0 + tx] = __float2bfloat16(t[tx][ty+r*8]);
  }
}

// ---------------- tiled transpose fp32->fp32: src[K][N] -> dst[N][K] ----------------
__global__ __launch_bounds__(256)
void transp_f32(const float* __restrict__ src, float* __restrict__ dst, int K, int N)
{
  __shared__ float t[32][33];
  int n0 = blockIdx.x*32, k0 = blockIdx.y*32;
  int tx = threadIdx.x & 31, ty = threadIdx.x >> 5;  // 32 x 8
#pragma unroll
  for (int r=0;r<4;r++){
    int kk = k0 + ty + r*8, nn = n0 + tx;
    t[ty+r*8][tx] = (nn < N) ? src[(long)kk*N + nn] : 0.f;
  }
  __syncthreads();
#pragma unroll
  for (int r=0;r<4;r++){
    int nn = n0 + ty + r*8;
    if (nn < N) dst[(long)nn*K + k0 + tx] = t[tx][ty+r*8];
  }
}

// ---------------- MFMA GEMM, 128x64 tile, xor-swizzled LDS (rows 32 bf16, g ^= row&3) ----------------
__global__ __launch_bounds__(256)
void gemm_bn64(const bf16* __restrict__ A, const bf16* __restrict__ Bt, void* __restrict__ C,
               int M, int N, int K, long sA, long sB, long sC, int relu, int outBf)
{
  A  += (long)blockIdx.z*sA;
  Bt += (long)blockIdx.z*sB;
  int m0 = blockIdx.y*128, n0 = blockIdx.x*64;
  __shared__ bf16 As[128*32];   // 8 KB
  __shared__ bf16 Bs[64*32];    // 4 KB
  int tid = threadIdx.x;
  int w = tid >> 6, lane = tid & 63;
  int quad = lane >> 4, l16 = lane & 15;
  int wm = w*32;
  f32x4 acc[2][4] = {};
  int srow = (lane >> 2);          // row within 16-row chunk
  int gsw  = ((lane & 3) ^ (srow & 3))*8;   // swizzled col group (8 bf16)
  const bf16* aBase = A + (long)m0*K;
  const bf16* bBase = Bt + (long)n0*K;
  int xr = (l16 & 3);              // read-side swizzle key (row&3 == l16&3)
  for (int k0=0; k0<K; k0+=32){
#pragma unroll
    for (int j=0;j<2;j++){
      int c = w*2 + j;
      int row = c*16 + srow;
      stage16(aBase + (long)row*K + k0 + gsw, As + c*512 + lane*8);
    }
    {
      int row = w*16 + srow;
      stage16(bBase + (long)row*K + k0 + gsw, Bs + w*512 + lane*8);
    }
    __syncthreads();
    bfrag af[2], bfv[4];
#pragma unroll
    for (int t=0;t<2;t++) af[t]  = *(const bfrag*)(As + (wm + t*16 + l16)*32 + ((quad ^ xr)*8));
#pragma unroll
    for (int t=0;t<4;t++) bfv[t] = *(const bfrag*)(Bs + (t*16 + l16)*32 + ((quad ^ xr)*8));
#pragma unroll
    for (int ti=0;ti<2;ti++)
#pragma unroll
      for (int tj=0;tj<4;tj++)
        acc[ti][tj] = __builtin_amdgcn_mfma_f32_16x16x32_bf16(af[ti], bfv[tj], acc[ti][tj], 0, 0, 0);
    __syncthreads();
  }
  long zoff = (long)blockIdx.z*sC;
  if (outBf){
    bf16* Cb = (bf16*)C + zoff;
#pragma unroll
    for (int ti=0;ti<2;ti++)
#pragma unroll
      for (int tj=0;tj<4;tj++)
#pragma unroll
        for (int r=0;r<4;r++){
          int row = m0 + wm + ti*16 + quad*4 + r;
          int col = n0 + tj*16 + l16;
          float v = acc[ti][tj][r];
          if (relu) v = fmaxf(v, 0.f);
          Cb[(long)row*N + col] = __float2bfloat16(v);
        }
  } else {
    float* Cf = (float*)C + zoff;
#pragma unroll
    for (int ti=0;ti<2;ti++)
#pragma unroll
      for (int tj=0;tj<4;tj++)
#pragma unroll
        for (int r=0;r<4;r++){
          int row = m0 + wm + ti*16 + quad*4 + r;
          int col = n0 + tj*16 + l16;
          float v = acc[ti][tj][r];
          if (relu) v = fmaxf(v, 0.f);
          Cf[(long)row*N + col] = v;
        }
  }
}

// ---------------- LayerNorm: fp32 in -> fp32 out (+ optional bf16 copy, + optional fused gate logits) ----------------
__global__ __launch_bounds__(256)
void ln_kernel(const float* __restrict__ src, const float* __restrict__ g, const float* __restrict__ bb,
               float* __restrict__ dstF, bf16* __restrict__ dstB,
               const float* __restrict__ gateW, float* __restrict__ glog2)
{
  int row = blockIdx.x, tid = threadIdx.x;
  __shared__ float red[256];
  __shared__ float gsum[4][E_];
  float v[3];
#pragma unroll
  for (int j=0;j<3;j++) v[j] = src[(long)row*D_ + tid + j*256];
  float s = v[0]+v[1]+v[2];
  red[tid]=s; __syncthreads();
  for (int o=128;o>0;o>>=1){ if(tid<o) red[tid]+=red[tid+o]; __syncthreads(); }
  float mean = red[0]*(1.0f/D_);
  __syncthreads();
  float sq = 0.f;
#pragma unroll
  for (int j=0;j<3;j++){ float d=v[j]-mean; sq += d*d; }
  red[tid]=sq; __syncthreads();
  for (int o=128;o>0;o>>=1){ if(tid<o) red[tid]+=red[tid+o]; __syncthreads(); }
  float rstd = rsqrtf(red[0]*(1.0f/D_) + 1e-5f);
  float ov[3];
#pragma unroll
  for (int j=0;j<3;j++){
    int d = tid + j*256;
    float o = (v[j]-mean)*rstd*g[d] + bb[d];
    ov[j] = o;
    dstF[(long)row*D_+d] = o;
    if (dstB) dstB[(long)row*D_+d] = __float2bfloat16(o);
  }
  if (gateW){
    float gp[E_] = {};
#pragma unroll
    for (int j=0;j<3;j++){
      int d = tid + j*256;
      const float* gw = gateW + (long)d*E_;
#pragma unroll
      for (int e=0;e<E_;e++) gp[e] += ov[j]*gw[e];
    }
#pragma unroll
    for (int off=1; off<64; off<<=1)
#pragma unroll
      for (int e=0;e<E_;e++) gp[e] += __shfl_xor(gp[e], off);
    if ((tid & 63) == 0)
#pragma unroll
      for (int e=0;e<E_;e++) gsum[tid>>6][e] = gp[e];
    __syncthreads();
    if (tid < E_)
      glog2[(long)row*E_ + tid] = gsum[0][tid]+gsum[1][tid]+gsum[2][tid]+gsum[3][tid];
  }
}

// ---------------- router logits + argmax: fp32, bank-friendly K-partition (seg stride 4 dwords) ----------------
#define RTOK 4
__global__ __launch_bounds__(768)
void router_argmax(const float* __restrict__ ln1, const float* __restrict__ WrT,
                   int* __restrict__ eidx, int* __restrict__ gHist)
{
  int tok0 = blockIdx.x*RTOK;
  int tid = threadIdx.x;
  int col = tid >> 3, seg = tid & 7;     // col 0..95 (= h*8+e), seg 0..7
  __shared__ float xrow[RTOK][D_];
  __shared__ float logits[RTOK][96];
  for (int i=tid; i<RTOK*D_; i+=768){
    int t = i / D_, dpos = i - t*D_;
    xrow[t][dpos] = ln1[(long)(tok0+t)*D_ + dpos];
  }
  __syncthreads();
  // thread (col,seg) sums elements {j*32 + seg*4 + 0..3}: LDS float4 reads cover all 32 banks
  // across the 8 segs (cols broadcast); WrT float4 reads coalesce 128B per col group.
  const float* wrow = WrT + (long)col*D_;
  float acc[RTOK] = {};
#pragma unroll
  for (int j=0;j<24;j++){
    int dbase = j*32 + seg*4;
    float4 w = *(const float4*)(wrow + dbase);
#pragma unroll
    for (int t=0;t<RTOK;t++){
      float4 xv = *(const float4*)(&xrow[t][dbase]);
      acc[t] += xv.x*w.x + xv.y*w.y + xv.z*w.z + xv.w*w.w;
    }
  }
#pragma unroll
  for (int off=1; off<8; off<<=1)
#pragma unroll
    for (int t=0;t<RTOK;t++) acc[t] += __shfl_xor(acc[t], off);
  if (seg == 0)
#pragma unroll
    for (int t=0;t<RTOK;t++) logits[t][col] = acc[t];
  __syncthreads();
  if (tid < RTOK*H_){
    int t = tid / H_, h = tid % H_;
    const float* p = &logits[t][h*8];
    float best = p[0]; int bi = 0;
#pragma unroll
    for (int e=1;e<8;e++){ float v=p[e]; if (v > best){ best=v; bi=e; } }
    eidx[(tok0+t)*H_ + h] = bi;
    atomicAdd(&gHist[h*E_ + bi], 1);
  }
}

// ---------------- selected V projection -> transposed bf16 vT[bh][f][s] ----------------
__global__ __launch_bounds__(64)
void vsel_kernel(const float* __restrict__ ln1, const float* __restrict__ Wv,
                 const int* __restrict__ eidx, bf16* __restrict__ vT)
{
  int blk = blockIdx.x;          // tok*H + h
  int h = blk % H_, tok = blk / H_;
  int b = tok >> 10, s = tok & 1023;
  int f = threadIdx.x;
  __shared__ float xs[DH_];
  xs[f] = ln1[(long)tok*D_ + h*DH_ + f];
  __syncthreads();
  int e = eidx[blk];
  const float* W = Wv + (long)(h*E_+e)*DH_*DH_;
  float acc = 0.f;
#pragma unroll 8
  for (int d=0; d<DH_; d++) acc += xs[d]*W[d*DH_ + f];
  vT[((long)(b*H_+h)*DH_ + f)*S_ + s] = __float2bfloat16(acc);
}

// ---------------- attention pass 1 (MFMA flash stats), xor-swizzled 64x64 LDS tiles ----------------
__global__ __launch_bounds__(256)
void attn_stats_mfma(const bf16* __restrict__ qkB, float* __restrict__ gM, float* __restrict__ gL)
{
  int s0 = blockIdx.x*64;
  int h = blockIdx.y, b = blockIdx.z;
  int tid = threadIdx.x;
  int w = tid >> 6, lane = tid & 63;
  int quad = lane >> 4, l16 = lane & 15;
  int x7 = l16 & 7;                    // read-side swizzle key (row&7 == l16&7)
  __shared__ bf16 ldsQ[64*64];
  __shared__ bf16 ldsK[64*64];
  const bf16* qbase = qkB + ((long)(b*S_ + s0))*QKLD + h*DH_;
#pragma unroll
  for (int j=0;j<2;j++){
    int c = j*256 + tid;
    int row = c >> 3;
    int gs = ((c & 7) ^ (row & 7))*8;
    stage16(qbase + (long)row*QKLD + gs, ldsQ + c*8);
  }
  float m_run[4] = {-1e30f,-1e30f,-1e30f,-1e30f};
  float l_run[4] = {0.f,0.f,0.f,0.f};
  const bf16* kbase = qkB + ((long)(b*S_))*QKLD + 768 + h*DH_;
  int ttEnd = s0 >> 6;
  for (int tt=0; tt<=ttEnd; tt++){
    __syncthreads();
#pragma unroll
    for (int j=0;j<2;j++){
      int c = j*256 + tid;
      int row = c >> 3;
      int gs = ((c & 7) ^ (row & 7))*8;
      stage16(kbase + (long)(tt*64 + row)*QKLD + gs, ldsK + c*8);
    }
    __syncthreads();
    bfrag af0 = *(const bfrag*)(ldsQ + (w*16 + l16)*64 + ((quad     ^ x7)*8));
    bfrag af1 = *(const bfrag*)(ldsQ + (w*16 + l16)*64 + (((quad+4) ^ x7)*8));
    f32x4 cfr[4];
#pragma unroll
    for (int j=0;j<4;j++){
      bfrag b0 = *(const bfrag*)(ldsK + (j*16 + l16)*64 + ((quad     ^ x7)*8));
      bfrag b1 = *(const bfrag*)(ldsK + (j*16 + l16)*64 + (((quad+4) ^ x7)*8));
      f32x4 z = {};
      z = __builtin_amdgcn_mfma_f32_16x16x32_bf16(af0, b0, z, 0,0,0);
      z = __builtin_amdgcn_mfma_f32_16x16x32_bf16(af1, b1, z, 0,0,0);
      cfr[j] = z;
    }
#pragma unroll
    for (int r=0;r<4;r++){
      int s_g = s0 + w*16 + quad*4 + r;
      float v[4];
#pragma unroll
      for (int j=0;j<4;j++){
        int t_g = tt*64 + j*16 + l16;
        v[j] = (t_g <= s_g) ? cfr[j][r]*0.125f : -1e30f;
      }
      float mt = fmaxf(fmaxf(v[0],v[1]), fmaxf(v[2],v[3]));
#pragma unroll
      for (int mm=1; mm<16; mm<<=1) mt = fmaxf(mt, __shfl_xor(mt, mm));
      float mn = fmaxf(m_run[r], mt);
      float sum = __expf(v[0]-mn)+__expf(v[1]-mn)+__expf(v[2]-mn)+__expf(v[3]-mn);
#pragma unroll
      for (int mm=1; mm<16; mm<<=1) sum += __shfl_xor(sum, mm);
      l_run[r] = l_run[r]*__expf(m_run[r]-mn) + sum;
      m_run[r] = mn;
    }
  }
  if (l16 == 0){
    long base = ((long)(b*H_ + h))*S_ + s0 + w*16 + quad*4;
#pragma unroll
    for (int r=0;r<4;r++){ gM[base+r] = m_run[r]; gL[base+r] = l_run[r]; }
  }
}

// ---------------- attention pass 2 (fused MFMA, transposed einsum), swizzled LDS + padded ldsS ----------------
__global__ __launch_bounds__(256)
void attn_pv(const bf16* __restrict__ qkB, const bf16* __restrict__ vT,
             const float* __restrict__ gM, const float* __restrict__ gL, float* __restrict__ aoH)
{
  int t0 = blockIdx.x*64;
  int h = blockIdx.y, b = blockIdx.z;
  int bh = b*H_ + h;
  int tid = threadIdx.x;
  int w = tid >> 6, lane = tid & 63;
  int quad = lane >> 4, l16 = lane & 15;
  int x7 = l16 & 7;
  __shared__ bf16 ldsK[64*64];
  __shared__ bf16 ldsQ[64*64];
  __shared__ bf16 ldsV[64*64];
  __shared__ bf16 ldsS[64*72];        // +8 pad breaks write-side bank conflicts
  __shared__ float smx[64], sli[64];
  const bf16* kbase = qkB + ((long)(b*S_ + t0))*QKLD + 768 + h*DH_;
#pragma unroll
  for (int j=0;j<2;j++){
    int c = j*256 + tid;
    int row = c >> 3;
    int gs = ((c & 7) ^ (row & 7))*8;
    stage16(kbase + (long)row*QKLD + gs, ldsK + c*8);
  }
  f32x4 accO[4] = {};
  const bf16* qbase = qkB + ((long)(b*S_))*QKLD + h*DH_;
  const bf16* vbase = vT + ((long)bh*DH_)*S_;
  for (int sb = t0>>6; sb < S_/64; sb++){
    __syncthreads();
#pragma unroll
    for (int j=0;j<2;j++){
      int c = j*256 + tid;
      int row = c >> 3;
      int gs = ((c & 7) ^ (row & 7))*8;
      stage16(qbase + (long)(sb*64 + row)*QKLD + gs, ldsQ + c*8);
      stage16(vbase + (long)row*S_ + sb*64 + gs, ldsV + c*8);
    }
    if (tid < 64){
      smx[tid] = gM[(long)bh*S_ + sb*64 + tid];
      sli[tid] = 1.0f / gL[(long)bh*S_ + sb*64 + tid];
    }
    __syncthreads();
    bfrag af0 = *(const bfrag*)(ldsK + (w*16 + l16)*64 + ((quad     ^ x7)*8));
    bfrag af1 = *(const bfrag*)(ldsK + (w*16 + l16)*64 + (((quad+4) ^ x7)*8));
    f32x4 cs[4];
#pragma unroll
    for (int j=0;j<4;j++){
      bfrag b0 = *(const bfrag*)(ldsQ + (j*16 + l16)*64 + ((quad     ^ x7)*8));
      bfrag b1 = *(const bfrag*)(ldsQ + (j*16 + l16)*64 + (((quad+4) ^ x7)*8));
      f32x4 z = {};
      z = __builtin_amdgcn_mfma_f32_16x16x32_bf16(af0, b0, z, 0,0,0);
      z = __builtin_amdgcn_mfma_f32_16x16x32_bf16(af1, b1, z, 0,0,0);
      cs[j] = z;
    }
#pragma unroll
    for (int j=0;j<4;j++)
#pragma unroll
      for (int r=0;r<4;r++){
        int t_loc = w*16 + quad*4 + r;
        int s_loc = j*16 + l16;
        float wgt = ((t0 + t_loc) <= (sb*64 + s_loc))
                  ? __expf(cs[j][r]*0.125f - smx[s_loc])*sli[s_loc] : 0.f;
        ldsS[t_loc*72 + s_loc] = __float2bfloat16(wgt);
      }
    bfrag pa0 = *(const bfrag*)(ldsS + (w*16 + l16)*72 + quad*8);
    bfrag pa1 = *(const bfrag*)(ldsS + (w*16 + l16)*72 + 32 + quad*8);
#pragma unroll
    for (int j=0;j<4;j++){
      bfrag b0 = *(const bfrag*)(ldsV + (j*16 + l16)*64 + ((quad     ^ x7)*8));
      bfrag b1 = *(const bfrag*)(ldsV + (j*16 + l16)*64 + (((quad+4) ^ x7)*8));
      accO[j] = __builtin_amdgcn_mfma_f32_16x16x32_bf16(pa0, b0, accO[j], 0,0,0);
      accO[j] = __builtin_amdgcn_mfma_f32_16x16x32_bf16(pa1, b1, accO[j], 0,0,0);
    }
  }
#pragma unroll
  for (int j=0;j<4;j++)
#pragma unroll
    for (int r=0;r<4;r++){
      int t_loc = w*16 + quad*4 + r;
      int f = j*16 + l16;
      aoH[((long)bh*S_ + t0 + t_loc)*DH_ + f] = accO[j][r];
    }
}

// ---------------- O projection + residual -> x1 ----------------
__global__ __launch_bounds__(64)
void oproj_kernel(const float* __restrict__ aoH, const float* __restrict__ Wo,
                  const int* __restrict__ eidx, const float* __restrict__ x,
                  float* __restrict__ x1)
{
  int blk = blockIdx.x;          // tok*H + h
  int h = blk % H_, tok = blk / H_;
  int b = tok >> 10, s = tok & 1023;
  int g = threadIdx.x;
  __shared__ float xs[DH_];
  xs[g] = aoH[((long)(b*H_+h)*S_ + s)*DH_ + g];
  __syncthreads();
  int e = eidx[blk];
  const float* W = Wo + (long)(h*E_+e)*DH_*DH_;
  float acc = 0.f;
#pragma unroll 8
  for (int f=0; f<DH_; f++) acc += xs[f]*W[f*DH_ + g];
  long idx = (long)tok*D_ + h*DH_ + g;
  x1[idx] = x[idx] + acc;
}

// ---------------- MoE routing: top-2, PARALLEL capacity prefix-scan, lists, aux losses ----------------
__global__ __launch_bounds__(256)
void route_kernel(const float* __restrict__ glog2, const int* __restrict__ gHist,
                  int* __restrict__ gI0, int* __restrict__ gI1,
                  int* __restrict__ gPos0, int* __restrict__ gPos1,
                  int* __restrict__ listTok, float* __restrict__ listW,
                  int* __restrict__ gCnt, float* __restrict__ auxOut)
{
  __shared__ unsigned char sI0[NTOK], sI1[NTOK];
  __shared__ float sP0[NTOK], sP1[NTOK];
  __shared__ short sPos0[NTOK], sPos1[NTOK];
  __shared__ int   sScan[256*E_];
  __shared__ int   sHist[H_*E_];
  __shared__ float sImp[E_];
  __shared__ int   sCnt[E_];
  int tid = threadIdx.x;
  if (tid < E_) sImp[tid] = 0.f;
  if (tid < H_*E_) sHist[tid] = gHist[tid];   // histogram precomputed by router_argmax
  for (int i=tid; i<NTOK; i+=256){
    const float* p = glog2 + (long)i*E_;
    float b0 = p[0]; int e0 = 0;
#pragma unroll
    for (int e=1;e<E_;e++){ float vv=p[e]; if (vv > b0){ b0=vv; e0=e; } }
    float b1v = -1e30f; int e1 = 0;
#pragma unroll
    for (int e=0;e<E_;e++){ if (e==e0) continue; float vv=p[e]; if (vv > b1v){ b1v=vv; e1=e; } }
    float ex = __expf(b1v - b0);
    float inv = 1.f/(1.f + ex);
    sI0[i] = (unsigned char)e0; sI1[i] = (unsigned char)e1;
    sP0[i] = inv; sP1[i] = ex*inv;
    gI0[i] = e0; gI1[i] = e1;
  }
  __syncthreads();
  {
    int myCnt[E_] = {};
#pragma unroll
    for (int j=0;j<16;j++){
      int i = tid*16 + j;
      int tok = i >> 1;
      int e = (i & 1) ? (int)sI1[tok] : (int)sI0[tok];
      myCnt[e]++;
    }
#pragma unroll
    for (int e=0;e<E_;e++) sScan[tid*E_+e] = myCnt[e];
    __syncthreads();
    for (int off=1; off<256; off<<=1){
      int v[E_];
      if (tid >= off){
#pragma unroll
        for (int e=0;e<E_;e++) v[e] = sScan[(tid-off)*E_+e];
      }
      __syncthreads();
      if (tid >= off){
#pragma unroll
        for (int e=0;e<E_;e++) sScan[tid*E_+e] += v[e];
      }
      __syncthreads();
    }
    int pref[E_];
#pragma unroll
    for (int e=0;e<E_;e++) pref[e] = tid ? sScan[(tid-1)*E_+e] : 0;
#pragma unroll
    for (int j=0;j<16;j++){
      int i = tid*16 + j;
      int tok = i >> 1;
      int e = (i & 1) ? (int)sI1[tok] : (int)sI0[tok];
      int pos = pref[e]++;
      short p = (pos < CAP_) ? (short)pos : (short)-1;
      if (i & 1) sPos1[tok] = p; else sPos0[tok] = p;
    }
    if (tid < E_){
      int cnt = sScan[255*E_ + tid];
      sCnt[tid] = cnt < CAP_ ? cnt : CAP_;
      gCnt[tid] = sCnt[tid];
    }
  }
  __syncthreads();
  for (int i=tid; i<NTOK; i+=256){
    int e0 = sI0[i], e1 = sI1[i];
    int p0i = sPos0[i], p1i = sPos1[i];
    float k0 = p0i >= 0 ? 1.f : 0.f, k1 = p1i >= 0 ? 1.f : 0.f;
    float p0 = sP0[i], p1 = sP1[i];
    float denom = p0*k0 + p1*k1 + 1e-9f;
    float w0 = p0*k0/denom, w1 = p1*k1/denom;
    if (p0i >= 0){ listTok[e0*CAP_+p0i] = i; listW[e0*CAP_+p0i] = w0; atomicAdd(&sImp[e0], w0); }
    if (p1i >= 0){ listTok[e1*CAP_+p1i] = i; listW[e1*CAP_+p1i] = w1; atomicAdd(&sImp[e1], w1); }
    gPos0[i] = p0i; gPos1[i] = p1i;
  }
  __syncthreads();
  if (tid == 0){
    float tot = 0.f;
    for (int i=0;i<H_*E_;i++) tot += (float)sHist[i]*(1.0f/NTOK)*0.01f;
    float a1 = 0.f;
    for (int i=0;i<H_*E_;i++){
      float p = ((float)sHist[i]*(1.0f/NTOK)*0.01f)/(tot + 1e-9f);
      a1 += p*p;
    }
    a1 *= (float)(H_*E_);
    float tcs = 0.f, ims = 0.f;
    for (int e=0;e<E_;e++){ tcs += (float)sCnt[e]; ims += sImp[e]; }
    float a2 = 0.f;
    for (int e=0;e<E_;e++) a2 += ((float)sCnt[e]/tcs)*(sImp[e]/ims);
    a2 *= (float)E_;
    auxOut[0] = a1 + a2;
  }
}

// ---------------- gather scaled tokens per expert -> bf16 Xg (CAPP rows/expert, zero-padded) ----------------
__global__ __launch_bounds__(256)
void gather_kernel(const float* __restrict__ ln2, const int* __restrict__ listTok,
                   const float* __restrict__ listW, const int* __restrict__ gCnt,
                   bf16* __restrict__ Xg)
{
  int blk = blockIdx.x;          // e*CAPP_ + r
  int e = blk / CAPP_, r = blk % CAPP_;
  int tid = threadIdx.x;
  bool live = r < gCnt[e];
  int tok = 0; float w = 0.f;
  if (live){ tok = listTok[e*CAP_+r]; w = listW[e*CAP_+r]; }
  for (int d=tid; d<D_; d+=256)
    Xg[(long)blk*D_ + d] = __float2bfloat16(live ? ln2[(long)tok*D_+d]*w : 0.f);
}

// ---------------- final combine: out = x1 + expert contributions (fp32 output) ----------------
__global__ __launch_bounds__(256)
void combine_kernel(const float* __restrict__ x1, const float* __restrict__ Yexp,
                    const int* __restrict__ gI0, const int* __restrict__ gI1,
                    const int* __restrict__ gPos0, const int* __restrict__ gPos1,
                    float* __restrict__ out)
{
  int i = blockIdx.x;
  int tid = threadIdx.x;
  int p0 = gPos0[i], p1 = gPos1[i];
  int e0 = gI0[i],  e1 = gI1[i];
  const float* y0 = Yexp + (long)(e0*CAPP_ + (p0 >= 0 ? p0 : 0))*D_;
  const float* y1 = Yexp + (long)(e1*CAPP_ + (p1 >= 0 ? p1 : 0))*D_;
  for (int d=tid; d<D_; d+=256){
    float v = x1[(long)i*D_+d];
    if (p0 >= 0) v += y0[d];
    if (p1 >= 0) v += y1[d];
    out[(long)i*D_+d] = v;
  }
}

extern "C" void kernel_launch(void* const* d_in, const int* in_sizes, int n_in,
                              void* d_out, int out_size, void* d_ws, size_t ws_size,
                              hipStream_t stream)
{
  const float* x    = (const float*)d_in[0];
  const float* W_q  = (const float*)d_in[2];
  const float* W_k  = (const float*)d_in[3];
  const float* W_v  = (const float*)d_in[4];
  const float* W_o  = (const float*)d_in[5];
  const float* W_r  = (const float*)d_in[6];
  const float* g1   = (const float*)d_in[7];
  const float* b1   = (const float*)d_in[8];
  const float* g2   = (const float*)d_in[9];
  const float* b2   = (const float*)d_in[10];
  const float* gate = (const float*)d_in[11];
  const float* W1   = (const float*)d_in[12];
  const float* W2   = (const float*)d_in[13];
  float* out = (float*)d_out;

  float* wsf = (float*)d_ws;
  // ---- workspace layout (float slots) ----
  const long oX1   = 0;          // 1,572,864
  const long oLnF  = 1572864;
  const long oLnB  = 3145728;    // bf16 2048x768
  const long oWcat = 3932160;    // bf16 1536x768 (ends 4521984)
  const long oWrT  = 4521984;    // fp32 96x768 = 73,728 (ends 4595712)
  const long oHist = 4595712;    // int 96 (attention (h,e) histogram)
  const long oGM   = 4718592;    // 24,576
  const long oGL   = 4743168;    // 24,576
  const long oEidx = 4767744;    // int 24,576
  const long oGlg2 = 4792320;    // 16,384
  const long oI0   = 4808704;
  const long oI1   = 4810752;
  const long oP0   = 4812800;
  const long oP1   = 4814848;
  const long oLT   = 4816896;
  const long oLW   = 4819456;
  const long oCnt  = 4822016;
  const long SB    = 4822528;    // shared overlay region
  // attention view: qkB bf16 @SB (1.57M) | vT bf16 @+1,572,864 (0.79M) | aoH fp32 @+2,359,296 (1.57M)
  // FFN view:       WT bf16 @SB (6.29M) | Xg @+6,291,456 | Hid @+7,471,104 | Yexp fp32 @+10,616,832
  const long TOTAL = SB + 12976128;   // 17,798,656 floats = 71,194,624 B
  if (ws_size < (size_t)TOTAL*4) return;

  float* x1    = wsf + oX1;
  float* lnbF  = wsf + oLnF;
  bf16*  lnbB  = (bf16*)(wsf + oLnB);
  bf16*  WcatB = (bf16*)(wsf + oWcat);
  float* WrT   = wsf + oWrT;
  int*   gHist = (int*)(wsf + oHist);
  float* gM    = wsf + oGM;
  float* gL    = wsf + oGL;
  int*   eidx  = (int*)(wsf + oEidx);
  float* glog2 = wsf + oGlg2;
  int*   gI0   = (int*)(wsf + oI0);
  int*   gI1   = (int*)(wsf + oI1);
  int*   gPos0 = (int*)(wsf + oP0);
  int*   gPos1 = (int*)(wsf + oP1);
  int*   lTok  = (int*)(wsf + oLT);
  float* lW    = wsf + oLW;
  int*   gCnt  = (int*)(wsf + oCnt);
  bf16*  qkB   = (bf16*)(wsf + SB);
  bf16*  vT    = (bf16*)(wsf + SB + 1572864);
  float* aoH   = wsf + SB + 2359296;
  bf16*  WT    = (bf16*)(wsf + SB);
  bf16*  Xg    = (bf16*)(wsf + SB + 6291456);
  bf16*  Hid   = (bf16*)(wsf + SB + 7471104);
  float* Yexp  = wsf + SB + 10616832;

  // ---- weight prep + hist zero ----
  hipMemsetAsync(gHist, 0, H_*E_*sizeof(int), stream);
  transp_cvt<<<dim3(24,24,1),256,0,stream>>>(W_q, WcatB, 768, 768, 0, 0, 0);
  transp_cvt<<<dim3(24,24,1),256,0,stream>>>(W_k, WcatB, 768, 768, 0, 0, 768);
  transp_f32<<<dim3(3,24,1),256,0,stream>>>(W_r, WrT, 768, 96);

  // ---- attention phase ----
  ln_kernel<<<NTOK,256,0,stream>>>(x, g1, b1, lnbF, lnbB, nullptr, nullptr);
  gemm_bn64<<<dim3(24,16,1),256,0,stream>>>(lnbB, WcatB, qkB, 2048, QKLD, 768, 0,0,0, 0, 1);
  router_argmax<<<NTOK/RTOK,768,0,stream>>>(lnbF, WrT, eidx, gHist);
  vsel_kernel<<<NTH,64,0,stream>>>(lnbF, W_v, eidx, vT);
  attn_stats_mfma<<<dim3(S_/64,H_,B_),256,0,stream>>>(qkB, gM, gL);
  attn_pv<<<dim3(S_/64,H_,B_),256,0,stream>>>(qkB, vT, gM, gL, aoH);
  oproj_kernel<<<NTH,64,0,stream>>>(aoH, W_o, eidx, x, x1);

  // ---- FFN phase ----
  ln_kernel<<<NTOK,256,0,stream>>>(x1, g2, b2, lnbF, nullptr, gate, glog2);  // fused gate logits
  route_kernel<<<1,256,0,stream>>>(glog2, gHist, gI0,gI1,gPos0,gPos1, lTok,lW,gCnt, out + (size_t)NTOK*D_);
  gather_kernel<<<E_*CAPP_,256,0,stream>>>(lnbF, lTok, lW, gCnt, Xg);
  transp_cvt<<<dim3(64,24,8),256,0,stream>>>(W1, WT, 768, 2048, (long)768*2048, (long)2048*768, 0);
  gemm_bn64<<<dim3(32,3,8),256,0,stream>>>(Xg, WT, Hid, CAPP_, DFF_, 768,
                                           (long)CAPP_*768, (long)2048*768, (long)CAPP_*2048, 1, 1);
  transp_cvt<<<dim3(24,64,8),256,0,stream>>>(W2, WT, 2048, 768, (long)2048*768, (long)768*2048, 0);
  gemm_bn64<<<dim3(12,3,8),256,0,stream>>>(Hid, WT, Yexp, CAPP_, 768, 2048,
                                           (long)CAPP_*2048, (long)768*2048, (long)CAPP_*768, 0, 0);
  combine_kernel<<<NTOK,256,0,stream>>>(x1, Yexp, gI0,gI1,gPos0,gPos1, out);
}